// Round 3
// baseline (792.834 us; speedup 1.0000x reference)
//
#include <hip/hip_runtime.h>
#include <hip/hip_bf16.h>
#include <math.h>

#define L_SEQ 64
#define NB    128
#define EMBD  512
#define HID   256
#define G4    1024      // 4*HID
#define NCOL  2048      // 2 dirs * 4H
#define DDIM  512       // 2*HID
#define MS    (L_SEQ*NB)   // 8192 rows per sentence
#define MTOT  (2*MS)       // 16384 combined rows

typedef __bf16 bf16_t;
typedef bf16_t bf16x8 __attribute__((ext_vector_type(8)));
typedef float  floatx4 __attribute__((ext_vector_type(4)));
typedef float  floatx8 __attribute__((ext_vector_type(8)));

__device__ __forceinline__ bf16x8 cvt_bf16x8(floatx8 v) {
    bf16x8 r;
    r[0]=(bf16_t)v[0]; r[1]=(bf16_t)v[1]; r[2]=(bf16_t)v[2]; r[3]=(bf16_t)v[3];
    r[4]=(bf16_t)v[4]; r[5]=(bf16_t)v[5]; r[6]=(bf16_t)v[6]; r[7]=(bf16_t)v[7];
    return r;
}

__device__ __forceinline__ void gload_lds16(const bf16_t* g, bf16_t* l) {
    __builtin_amdgcn_global_load_lds(
        (const __attribute__((address_space(1))) unsigned int*)(g),
        (__attribute__((address_space(3))) unsigned int*)(l), 16, 0, 0);
}

__device__ __forceinline__ float fsigmoid(float x) {
    return __builtin_amdgcn_rcpf(1.0f + __expf(-x));
}
__device__ __forceinline__ float ftanh(float x) {
    return 1.0f - 2.0f * __builtin_amdgcn_rcpf(__expf(2.0f*x) + 1.0f);
}

// ---------------------------------------------------------------------------
// Pack kernels (unchanged from R2)
// ---------------------------------------------------------------------------
__global__ __launch_bounds__(256) void k_pack_a(const int* __restrict__ t1,
                                                const int* __restrict__ t2,
                                                const float* __restrict__ emb,
                                                bf16_t* __restrict__ A)
{
    int gid = blockIdx.x*256 + threadIdx.x;
    int row = gid >> 6;
    int k8  = (gid & 63) * 8;
    int tok = (row < MS) ? t1[row] : t2[row - MS];
    floatx8 v = *(const floatx8*)(emb + (size_t)tok*EMBD + k8);
    *(bf16x8*)(A + (size_t)row*EMBD + k8) = cvt_bf16x8(v);
}

__global__ __launch_bounds__(256) void k_pack_b(const float* __restrict__ wih_f,
                                                const float* __restrict__ wih_b,
                                                bf16_t* __restrict__ B)
{
    int gid = blockIdx.x*256 + threadIdx.x;
    int n   = gid >> 6;
    int k8  = (gid & 63) * 8;
    const float* src = (n >= 1024) ? (wih_b + (size_t)(n-1024)*EMBD)
                                   : (wih_f + (size_t)n*EMBD);
    *(bf16x8*)(B + (size_t)n*EMBD + k8) = cvt_bf16x8(*(const floatx8*)(src + k8));
}

__global__ __launch_bounds__(256) void k_pack_whh(const float* __restrict__ whh_f,
                                                  const float* __restrict__ whh_b,
                                                  bf16_t* __restrict__ whhB)
{
    int gid = blockIdx.x*256 + threadIdx.x;
    int r2  = gid >> 5;
    int k8  = (gid & 31) * 8;
    const float* src = (r2 >= 1024) ? (whh_b + (size_t)(r2-1024)*HID)
                                    : (whh_f + (size_t)r2*HID);
    *(bf16x8*)(whhB + (size_t)r2*HID + k8) = cvt_bf16x8(*(const floatx8*)(src + k8));
}

__global__ __launch_bounds__(256) void k_pack_bias(const float* __restrict__ bih_f,
                                                   const float* __restrict__ bhh_f,
                                                   const float* __restrict__ bih_b,
                                                   const float* __restrict__ bhh_b,
                                                   float* __restrict__ bias)
{
    int n = blockIdx.x*256 + threadIdx.x;
    bias[n] = (n >= 1024) ? (bih_b[n-1024] + bhh_b[n-1024])
                          : (bih_f[n] + bhh_f[n]);
}

// ---------------------------------------------------------------------------
// xg GEMM (m97-style, unchanged from R2)
// ---------------------------------------------------------------------------
__global__ __launch_bounds__(256) void xg_gemm2(const bf16_t* __restrict__ A,
                                                const bf16_t* __restrict__ B,
                                                const float* __restrict__ bias,
                                                float* __restrict__ xg)
{
    __shared__ bf16_t As[128*32];
    __shared__ bf16_t Bs[128*32];
    const int tid  = threadIdx.x;
    const int wid  = tid >> 6;
    const int lane = tid & 63;
    const int l15  = lane & 15;
    const int quad = lane >> 4;
    const int m0   = blockIdx.y * 128;
    const int n0   = blockIdx.x * 128;
    const int mw   = (wid & 1) * 64;
    const int nw   = (wid >> 1) * 64;

    float biasv[4];
#pragma unroll
    for (int ni = 0; ni < 4; ++ni) biasv[ni] = bias[n0 + nw + ni*16 + l15];

    const int srow = tid >> 2;
    const int sk8  = (tid & 3) * 8;

    floatx4 acc[4][4] = {};
    for (int kk = 0; kk < EMBD; kk += 32) {
#pragma unroll
        for (int inst = 0; inst < 2; ++inst) {
            gload_lds16(A + (size_t)(m0 + inst*64 + srow)*EMBD + kk + sk8,
                        As + inst*2048 + wid*512);
            gload_lds16(B + (size_t)(n0 + inst*64 + srow)*EMBD + kk + sk8,
                        Bs + inst*2048 + wid*512);
        }
        __syncthreads();
        bf16x8 a[4], b[4];
#pragma unroll
        for (int mi = 0; mi < 4; ++mi)
            a[mi] = *(const bf16x8*)(As + (mw + mi*16 + l15)*32 + quad*8);
#pragma unroll
        for (int ni = 0; ni < 4; ++ni)
            b[ni] = *(const bf16x8*)(Bs + (nw + ni*16 + l15)*32 + quad*8);
#pragma unroll
        for (int mi = 0; mi < 4; ++mi)
#pragma unroll
            for (int ni = 0; ni < 4; ++ni)
                acc[mi][ni] = __builtin_amdgcn_mfma_f32_16x16x32_bf16(
                                  a[mi], b[ni], acc[mi][ni], 0, 0, 0);
        __syncthreads();
    }
#pragma unroll
    for (int mi = 0; mi < 4; ++mi)
#pragma unroll
        for (int ni = 0; ni < 4; ++ni)
#pragma unroll
            for (int r = 0; r < 4; ++r) {
                int m = m0 + mw + mi*16 + quad*4 + r;
                int n = n0 + nw + ni*16 + l15;
                xg[(size_t)m*NCOL + n] = acc[mi][ni][r] + biasv[ni];
            }
}

// ---------------------------------------------------------------------------
// LSTM scan v3. Grid (16,2) x 512 threads. M=16 rows/block, N=1024 gate cols.
// B residency: ks0-2 in VGPR (24 frags), ks3-4 in LDS (16 frags/wave, 128 KB,
// preloaded once via global_load_lds), ks5-7 streamed from L2 each step with
// batched issue (consumed last; vmcnt FIFO hides latency behind resident MFMAs).
// h ping-pong in LDS as bf16 in exact A-frag layout -> conflict-free b128.
// ---------------------------------------------------------------------------
__global__ __launch_bounds__(512) void lstm_scan3(
    const bf16_t* __restrict__ whhB,   // [2][1024][256] bf16
    const float*  __restrict__ xg,     // [2*8192][2048] fp32
    float* __restrict__ o1, float* __restrict__ o2)
{
    extern __shared__ char smem[];
    bf16_t* hb = (bf16_t*)smem;                 // 2 frames x 4096 bf16 (A-frag layout)
    bf16_t* BL = (bf16_t*)(smem + 16384);       // 8 waves x 16 frags x 512 bf16 = 128 KB

    const int tid  = threadIdx.x;
    const int wid  = tid >> 6;
    const int lane = tid & 63;
    const int l15  = lane & 15;
    const int quad = lane >> 4;
    const int bc   = blockIdx.x;          // 0..15: sent*8 + chunk
    const int dr   = blockIdx.y;          // 0..1
    const int sent = bc >> 3;
    const int bloc0 = (bc & 7) * 16;
    float* o = sent ? o2 : o1;
    const float* xgs = xg + (size_t)sent * MS * NCOL;
    const bf16_t* bb = whhB + (size_t)dr * (1024*HID);

    // ---- LDS B preload (ks=3,4): dest is wave-uniform base + lane*16
#pragma unroll
    for (int t = 0; t < 8; ++t) {
        const int nc = (t>>1)*256 + wid*32 + (t&1)*16;
#pragma unroll
        for (int ksl = 0; ksl < 2; ++ksl) {
            const bf16_t* gp = bb + (size_t)(nc + l15)*HID + (3+ksl)*32 + quad*8;
            bf16_t* lp = BL + ((wid*8 + t)*2 + ksl)*512;
            gload_lds16(gp, lp);
        }
    }
    // ---- VGPR B cache (ks=0..2): 24 frags = 96 VGPRs
    bf16x8 bwc[8][3];
#pragma unroll
    for (int t = 0; t < 8; ++t) {
        const int nc = (t>>1)*256 + wid*32 + (t&1)*16;
#pragma unroll
        for (int ks = 0; ks < 3; ++ks)
            bwc[t][ks] = *(const bf16x8*)(bb + (size_t)(nc + l15)*HID + ks*32 + quad*8);
    }
    // zero h frame 0
    for (int i = tid; i < 4096; i += 512) hb[i] = (bf16_t)0.0f;
    __syncthreads();   // drains global_load_lds (vmcnt 0 before barrier)

    float cst[8] = {};   // c state: [s*4+r]
    int pp = 0;

    for (int st = 0; st < L_SEQ; ++st) {
        const int lt = dr ? (L_SEQ-1-st) : st;
        // stop LICM from hoisting the loop-invariant streamed/LDS B loads
        asm volatile("" ::: "memory");

        // streamed B batches ks=5,6 (issued first; consumed last)
        bf16x8 sb5[8], sb6[8], sb7[8];
#pragma unroll
        for (int t = 0; t < 8; ++t) {
            const int nc = (t>>1)*256 + wid*32 + (t&1)*16;
            sb5[t] = *(const bf16x8*)(bb + (size_t)(nc + l15)*HID + 5*32 + quad*8);
        }
#pragma unroll
        for (int t = 0; t < 8; ++t) {
            const int nc = (t>>1)*256 + wid*32 + (t&1)*16;
            sb6[t] = *(const bf16x8*)(bb + (size_t)(nc + l15)*HID + 6*32 + quad*8);
        }
        // A frags from hbuf[pp] (conflict-free contiguous 16B/lane)
        bf16x8 af[8];
        const bf16_t* hf = hb + pp*4096;
#pragma unroll
        for (int ks = 0; ks < 8; ++ks)
            af[ks] = *(const bf16x8*)(hf + ((ks*4 + quad)*16 + l15)*8);

        floatx4 acc[8] = {};
        // ks 0..2: VGPR-resident B
#pragma unroll
        for (int ks = 0; ks < 3; ++ks)
#pragma unroll
            for (int t = 0; t < 8; ++t)
                acc[t] = __builtin_amdgcn_mfma_f32_16x16x32_bf16(
                             af[ks], bwc[t][ks], acc[t], 0, 0, 0);
        // issue streamed batch ks=7
#pragma unroll
        for (int t = 0; t < 8; ++t) {
            const int nc = (t>>1)*256 + wid*32 + (t&1)*16;
            sb7[t] = *(const bf16x8*)(bb + (size_t)(nc + l15)*HID + 7*32 + quad*8);
        }
        // ks 3,4: LDS-resident B
#pragma unroll
        for (int ksl = 0; ksl < 2; ++ksl)
#pragma unroll
            for (int t = 0; t < 8; ++t) {
                bf16x8 bl = *(const bf16x8*)(BL + ((wid*8 + t)*2 + ksl)*512 + lane*8);
                acc[t] = __builtin_amdgcn_mfma_f32_16x16x32_bf16(
                             af[3+ksl], bl, acc[t], 0, 0, 0);
            }
        // xg loads for this step (consumed in epilogue)
        float xgv[8][4];
#pragma unroll
        for (int t = 0; t < 8; ++t) {
            const int gc = dr*G4 + (t>>1)*256 + wid*32 + (t&1)*16 + l15;
#pragma unroll
            for (int r = 0; r < 4; ++r)
                xgv[t][r] = xgs[(size_t)(lt*NB + bloc0 + quad*4 + r)*NCOL + gc];
        }
        // ks 5,6,7: streamed B
#pragma unroll
        for (int t = 0; t < 8; ++t)
            acc[t] = __builtin_amdgcn_mfma_f32_16x16x32_bf16(af[5], sb5[t], acc[t], 0, 0, 0);
#pragma unroll
        for (int t = 0; t < 8; ++t)
            acc[t] = __builtin_amdgcn_mfma_f32_16x16x32_bf16(af[6], sb6[t], acc[t], 0, 0, 0);
#pragma unroll
        for (int t = 0; t < 8; ++t)
            acc[t] = __builtin_amdgcn_mfma_f32_16x16x32_bf16(af[7], sb7[t], acc[t], 0, 0, 0);

        // epilogue: t = grp*2+s; grp order i,f,g,o
        bf16_t* hw = hb + (pp^1)*4096;
#pragma unroll
        for (int s = 0; s < 2; ++s) {
            const int j = wid*32 + s*16 + l15;
#pragma unroll
            for (int r = 0; r < 4; ++r) {
                const int m = quad*4 + r;
                float gi = acc[0*2+s][r] + xgv[0*2+s][r];
                float gf = acc[1*2+s][r] + xgv[1*2+s][r];
                float gg = acc[2*2+s][r] + xgv[2*2+s][r];
                float go = acc[3*2+s][r] + xgv[3*2+s][r];
                float cv = fsigmoid(gf)*cst[s*4+r] + fsigmoid(gi)*ftanh(gg);
                cst[s*4+r] = cv;
                float hv = fsigmoid(go)*ftanh(cv);
                o[(size_t)(lt*NB + bloc0 + m)*DDIM + dr*HID + j] = hv;
                // A-frag layout: element (m, k=j) -> ((k>>3)*16+m)*8 + (k&7)
                hw[((j>>3)*16 + m)*8 + (j&7)] = (bf16_t)hv;
            }
        }
        __syncthreads();
        pp ^= 1;
    }
}

// ---------------------------------------------------------------------------
// mp1[b,d] = max_l o1[l,b,d]
// ---------------------------------------------------------------------------
__global__ __launch_bounds__(256) void k_mp1(const float* __restrict__ o1,
                                             float* __restrict__ mp1)
{
    int gid = blockIdx.x*256 + threadIdx.x;
    float m = -3.402823466e+38f;
    for (int l = 0; l < L_SEQ; ++l)
        m = fmaxf(m, o1[(size_t)l*(NB*DDIM) + gid]);
    mp1[gid] = m;
}

// ---------------------------------------------------------------------------
// attention + sim (unchanged)
// ---------------------------------------------------------------------------
__global__ __launch_bounds__(256) void k_att(const float* __restrict__ o2,
                                             const float* __restrict__ mp1,
                                             float* __restrict__ sim)
{
    const int b   = blockIdx.x;
    const int tid = threadIdx.x;
    const int l   = tid & 63;
    const int cp  = tid >> 6;
    __shared__ float spart[256];
    __shared__ float satt[64], sexp[64], ssm[64];
    __shared__ float red[256];

    const float* o2b = o2  + (size_t)b*32768;
    const float* mpb = mp1 + b*DDIM;

    float p = 0.0f;
    for (int d = cp*128; d < cp*128 + 128; ++d)
        p += mpb[d] * o2b[d*64 + l];
    spart[tid] = p;
    __syncthreads();
    if (tid < 64)
        satt[tid] = spart[tid] + spart[tid+64] + spart[tid+128] + spart[tid+192];
    __syncthreads();
    if (tid < 64) {
        float mx = satt[0];
        for (int i = 1; i < 64; ++i) mx = fmaxf(mx, satt[i]);
        sexp[tid] = expf(satt[tid] - mx);
    }
    __syncthreads();
    if (tid < 64) {
        float s = 0.0f;
        for (int i = 0; i < 64; ++i) s += sexp[i];
        ssm[tid] = sexp[tid] / s;
    }
    __syncthreads();

    float np0 = 0.0f, np1 = 0.0f;
    for (int l2 = 0; l2 < 64; ++l2) {
        float smv = ssm[l2];
        np0 += smv * o2b[l2*DDIM + tid];
        np1 += smv * o2b[l2*DDIM + tid + 256];
    }
    float diff = fabsf(mpb[tid] - np0) + fabsf(mpb[tid+256] - np1);
    red[tid] = diff;
    __syncthreads();
    for (int s = 128; s > 0; s >>= 1) {
        if (tid < s) red[tid] += red[tid + s];
        __syncthreads();
    }
    if (tid == 0) sim[b] = expf(-red[0]);
}

// ---------------------------------------------------------------------------
// commonWords + masked maxes (unchanged)
// ---------------------------------------------------------------------------
__global__ __launch_bounds__(256) void k_common(
    const int*   __restrict__ t1, const int* __restrict__ t2,
    const float* __restrict__ o1, const float* __restrict__ o2,
    float* __restrict__ e1h, float* __restrict__ e2h)
{
    const int b   = blockIdx.x;
    const int tid = threadIdx.x;
    __shared__ int ss1[64];
    __shared__ int smask[64];
    __shared__ int spos[64];
    __shared__ int sany;
    if (tid == 0) sany = 0;
    if (tid < 64) ss1[tid] = t1[tid*NB + b];
    __syncthreads();
    if (tid < 64) {
        int s2 = t2[tid*NB + b];
        int dmax = -1;
        for (int j = 0; j < 64; ++j)
            if (ss1[j] == s2) dmax = j;
        int mk = (dmax > 1) && (s2 > 0);
        smask[tid] = mk;
        spos[tid]  = dmax < 0 ? 0 : dmax;
        if (mk) sany = 1;
    }
    __syncthreads();
    int has = sany;
#pragma unroll
    for (int half = 0; half < 2; ++half) {
        int dd = tid + half*256;
        float m1 = -3.402823466e+38f, m2 = -3.402823466e+38f;
        for (int i = 0; i < 64; ++i) {
            if (smask[i]) {
                m1 = fmaxf(m1, o1[(size_t)spos[i]*(NB*DDIM) + b*DDIM + dd]);
                m2 = fmaxf(m2, o2[(size_t)i      *(NB*DDIM) + b*DDIM + dd]);
            }
        }
        e1h[b*DDIM + dd] = has ? m1 : 0.0f;
        e2h[b*DDIM + dd] = has ? m2 : 0.0f;
    }
}

// ---------------------------------------------------------------------------
extern "C" void kernel_launch(void* const* d_in, const int* in_sizes, int n_in,
                              void* d_out, int out_size, void* d_ws, size_t ws_size,
                              hipStream_t stream)
{
    (void)in_sizes; (void)n_in; (void)out_size; (void)ws_size;
    const int*   t1    = (const int*)d_in[0];
    const int*   t2    = (const int*)d_in[1];
    const float* emb   = (const float*)d_in[2];
    const float* wih_f = (const float*)d_in[3];
    const float* whh_f = (const float*)d_in[4];
    const float* bih_f = (const float*)d_in[5];
    const float* bhh_f = (const float*)d_in[6];
    const float* wih_b = (const float*)d_in[7];
    const float* whh_b = (const float*)d_in[8];
    const float* bih_b = (const float*)d_in[9];
    const float* bhh_b = (const float*)d_in[10];
    float* out = (float*)d_out;

    char* ws = (char*)d_ws;
    size_t off = 0;
    auto carve = [&](size_t bytes) -> void* {
        void* p = ws + off;
        off = (off + bytes + 255) & ~(size_t)255;
        return p;
    };
    float*  o1   = (float*)carve(sizeof(float)*(size_t)L_SEQ*NB*DDIM);
    float*  o2   = (float*)carve(sizeof(float)*(size_t)L_SEQ*NB*DDIM);
    bf16_t* whhB = (bf16_t*)carve(sizeof(bf16_t)*2*1024*HID);
    bf16_t* Bw   = (bf16_t*)carve(sizeof(bf16_t)*(size_t)NCOL*EMBD);
    float*  bias = (float*)carve(sizeof(float)*NCOL);
    float*  mp1  = (float*)carve(sizeof(float)*NB*DDIM);
    float*  xgb  = (float*)carve(sizeof(float)*(size_t)MTOT*NCOL);   // 134 MB
    bf16_t* A    = (bf16_t*)o1;   // A dead before scan writes o1

    // allow 144 KB dynamic LDS for the scan (gfx950 HW max 160 KB/WG)
    static bool attr_done = false;
    (void)attr_done;
    hipFuncSetAttribute((const void*)lstm_scan3,
                        hipFuncAttributeMaxDynamicSharedMemorySize, 147456);

    hipLaunchKernelGGL(k_pack_a,    dim3(4096), dim3(256), 0, stream, t1, t2, emb, A);
    hipLaunchKernelGGL(k_pack_b,    dim3(512),  dim3(256), 0, stream, wih_f, wih_b, Bw);
    hipLaunchKernelGGL(k_pack_whh,  dim3(256),  dim3(256), 0, stream, whh_f, whh_b, whhB);
    hipLaunchKernelGGL(k_pack_bias, dim3(8),    dim3(256), 0, stream,
                       bih_f, bhh_f, bih_b, bhh_b, bias);

    hipLaunchKernelGGL(xg_gemm2, dim3(16, 128), dim3(256), 0, stream, A, Bw, bias, xgb);

    hipLaunchKernelGGL(lstm_scan3, dim3(16, 2), dim3(512), 147456, stream,
                       whhB, xgb, o1, o2);

    hipLaunchKernelGGL(k_mp1,    dim3(256), dim3(256), 0, stream, o1, mp1);
    hipLaunchKernelGGL(k_att,    dim3(128), dim3(256), 0, stream, o2, mp1, out);
    hipLaunchKernelGGL(k_common, dim3(128), dim3(256), 0, stream,
                       t1, t2, o1, o2, out + NB, out + NB + NB*DDIM);
}